// Round 1
// baseline (550.764 us; speedup 1.0000x reference)
//
#include <hip/hip_runtime.h>

typedef float f32x4 __attribute__((ext_vector_type(4)));
typedef __bf16 bf16x8 __attribute__((ext_vector_type(8)));

#define HIDDEN 128

// ---- workspace layout: bf16 weight-fragment region, then f32 region ----
// bf16 element offsets:
#define WB_W1E 0
#define WB_W2E 4096
#define WB_W3E 20480
#define WB_W1N 22528
#define WB_W2N 26624
#define WB_W3N 43008
#define WB_W1D 45056
#define WB_W2D 49152
#define WB_W3D 65536
#define WB_W4D 81920
#define WB_TOTAL 83968  // elements; *2 = 167936 bytes (16B aligned)

// ================= weight prep: f32 row-major [K][N] -> fragmented bf16 =================
// frag fi = kt*CT+ct, within frag: lane-major 8 elems:
//   value = W[kt*32 + (lane>>4)*8 + j][ct*16 + (lane&15)]  (zero-padded)
__global__ void k_prep(const float* __restrict__ ew1, const float* __restrict__ ew2,
                       const float* __restrict__ ew3, const float* __restrict__ nw1,
                       const float* __restrict__ nw2, const float* __restrict__ nw3,
                       const float* __restrict__ dw1, const float* __restrict__ dw2,
                       const float* __restrict__ dw3, const float* __restrict__ dw4,
                       __bf16* __restrict__ wb) {
  int gid = blockIdx.x * 256 + threadIdx.x;
  if (gid >= WB_TOTAL) return;
  const float* srcs[10] = {ew1, ew2, ew3, nw1, nw2, nw3, dw1, dw2, dw3, dw4};
  const int Ks[10] = {9, 128, 128, 5, 128, 128, 5, 128, 128, 128};
  const int Ns[10] = {128, 128, 3, 128, 128, 1, 128, 128, 128, 1};
  const int CTs[10] = {8, 8, 1, 8, 8, 1, 8, 8, 8, 1};
  const int cum[11] = {0, 4096, 20480, 22528, 26624, 43008, 45056, 49152, 65536, 81920, 83968};
  int seg = 0;
  while (gid >= cum[seg + 1]) seg++;
  int li = gid - cum[seg];
  int j = li & 7;
  int lane = (li >> 3) & 63;
  int fi = li >> 9;
  int CT = CTs[seg];
  int ct = fi % CT;
  int kt = fi / CT;
  int k = kt * 32 + ((lane >> 4) << 3) + j;
  int n = ct * 16 + (lane & 15);
  float v = 0.f;
  if (k < Ks[seg] && n < Ns[seg]) v = srcs[seg][k * Ns[seg] + n];
  wb[gid] = (__bf16)v;
}

// ================= init =================
__global__ void k_init_nodes(const float* __restrict__ y_prev, float* __restrict__ x4,
                             float* __restrict__ deg, float* __restrict__ aggr, int n) {
  int i = blockIdx.x * 256 + threadIdx.x;
  if (i < n) {
    x4[i] = y_prev[i];
    deg[i] = 0.f;
    f32x4 z = {0.f, 0.f, 0.f, 0.f};
    *(f32x4*)(aggr + 4 * i) = z;
  }
}

__global__ void k_init_edges(const float* __restrict__ Xc, const float* __restrict__ y_prev,
                             const int* __restrict__ src, const int* __restrict__ dstp,
                             float* __restrict__ pe, float* __restrict__ ea,
                             float* __restrict__ deg, int E) {
  int e = blockIdx.x * 256 + threadIdx.x;
  if (e < E) {
    int s = src[e], d = dstp[e];
    float dx = Xc[d * 6 + 0] - Xc[s * 6 + 0];
    float dy = Xc[d * 6 + 1] - Xc[s * 6 + 1];
    float dz = Xc[d * 6 + 2] - Xc[s * 6 + 2];
    float nr = sqrtf(dx * dx + dy * dy + dz * dz);
    f32x4 p = {dx, dy, dz, nr};
    *(f32x4*)(pe + 4 * e) = p;
    float w = y_prev[d] - y_prev[s];
    f32x4 a = {w * dx, w * dy, w * dz, 0.f};
    *(f32x4*)(ea + 4 * e) = a;
    atomicAdd(deg + d, 1.0f);
  }
}

// ================= MFMA helpers =================
// A-frag read from LDS act[16][128]: A[row=l&15][k=(l>>4)*8+j]
// D-frag: col=l&15, row=(l>>4)*4+reg

__device__ __forceinline__ void load_res8(const __bf16* __restrict__ Wf, int lane,
                                          bf16x8 (&wr)[4][8]) {
#pragma unroll
  for (int kt = 0; kt < 4; kt++)
#pragma unroll
    for (int ct = 0; ct < 8; ct++)
      wr[kt][ct] = *(const bf16x8*)(Wf + ((kt * 8 + ct) << 9) + lane * 8);
}

__device__ __forceinline__ void load_res1(const __bf16* __restrict__ Wf, int lane,
                                          bf16x8 (&wr)[4]) {
#pragma unroll
  for (int kt = 0; kt < 4; kt++) wr[kt] = *(const bf16x8*)(Wf + (kt << 9) + lane * 8);
}

template <int KT>
__device__ __forceinline__ void mlp_layer_gB(const __bf16* actw, int col, int krow, int lane,
                                             const __bf16* __restrict__ Wf, f32x4 (&acc)[8]) {
#pragma unroll
  for (int kt = 0; kt < KT; kt++) {
    bf16x8 a = *(const bf16x8*)(actw + col * HIDDEN + kt * 32 + krow * 8);
#pragma unroll
    for (int ct = 0; ct < 8; ct++) {
      bf16x8 b = *(const bf16x8*)(Wf + ((kt * 8 + ct) << 9) + lane * 8);
      acc[ct] = __builtin_amdgcn_mfma_f32_16x16x32_bf16(a, b, acc[ct], 0, 0, 0);
    }
  }
}

__device__ __forceinline__ void mlp_layer_rB(const __bf16* actw, int col, int krow,
                                             const bf16x8 (&wr)[4][8], f32x4 (&acc)[8]) {
#pragma unroll
  for (int kt = 0; kt < 4; kt++) {
    bf16x8 a = *(const bf16x8*)(actw + col * HIDDEN + kt * 32 + krow * 8);
#pragma unroll
    for (int ct = 0; ct < 8; ct++)
      acc[ct] = __builtin_amdgcn_mfma_f32_16x16x32_bf16(a, wr[kt][ct], acc[ct], 0, 0, 0);
  }
}

template <int KT>
__device__ __forceinline__ f32x4 mlp_out_rB(const __bf16* actw, int col, int krow,
                                            const bf16x8 (&wr)[4], f32x4 acc) {
#pragma unroll
  for (int kt = 0; kt < KT; kt++) {
    bf16x8 a = *(const bf16x8*)(actw + col * HIDDEN + kt * 32 + krow * 8);
    acc = __builtin_amdgcn_mfma_f32_16x16x32_bf16(a, wr[kt], acc, 0, 0, 0);
  }
  return acc;
}

// relu + stage D-layout accs into LDS act[16][128] bf16
__device__ __forceinline__ void stage_relu(__bf16* actw, int col, int krow,
                                           const f32x4 (&acc)[8]) {
  int orow = krow * 4;
#pragma unroll
  for (int ct = 0; ct < 8; ct++)
#pragma unroll
    for (int r = 0; r < 4; r++) {
      float v = acc[ct][r];
      v = v > 0.f ? v : 0.f;
      actw[(orow + r) * HIDDEN + ct * 16 + col] = (__bf16)v;
    }
}

// ================= edge pass =================
struct ED {
  int s, d;
  f32x4 pe4, ea4;
};

__device__ __forceinline__ ED load_ed(int tile, int col, int E, const int* __restrict__ src,
                                      const int* __restrict__ dstp, const float* __restrict__ pe,
                                      const float* __restrict__ ea) {
  int e = tile * 16 + col;
  if (e >= E) e = E - 1;
  ED r;
  r.s = src[e];
  r.d = dstp[e];
  r.pe4 = *(const f32x4*)(pe + 4 * e);
  r.ea4 = *(const f32x4*)(ea + 4 * e);
  return r;
}

__global__ __launch_bounds__(256, 2) void k_edge(
    const float* __restrict__ x4, const float* __restrict__ pe, float* __restrict__ ea,
    const int* __restrict__ src, const int* __restrict__ dstp, const __bf16* __restrict__ W1f,
    const __bf16* __restrict__ W2f, const __bf16* __restrict__ W3f, const float* __restrict__ b1,
    const float* __restrict__ b2, const float* __restrict__ b3, float* __restrict__ aggr,
    int ntiles, int E) {
  __shared__ __bf16 act[4][16 * HIDDEN];
  int l = threadIdx.x & 63;
  int widx = threadIdx.x >> 6;
  __bf16* actw = act[widx];
  int wgid = blockIdx.x * 4 + widx;
  int nw = gridDim.x * 4;
  int col = l & 15;
  int krow = l >> 4;
  int orow = krow * 4;

  bf16x8 w2r[4][8];
  load_res8(W2f, l, w2r);
  bf16x8 w3r[4];
  load_res1(W3f, l, w3r);

  float b1c[8], b2c[8];
#pragma unroll
  for (int ct = 0; ct < 8; ct++) {
    b1c[ct] = b1[ct * 16 + col];
    b2c[ct] = b2[ct * 16 + col];
  }
  float b3c = (col < 3) ? b3[col] : 0.f;

  int tile = wgid;
  ED cur;
  if (tile < ntiles) cur = load_ed(tile, col, E, src, dstp, pe, ea);

  while (tile < ntiles) {
    int nt = tile + nw;
    ED nxt = cur;
    if (nt < ntiles) nxt = load_ed(nt, col, E, src, dstp, pe, ea);

    // keep per-tile W1 loads un-hoisted (L1-resident)
    const __bf16* w1p = W1f;
    asm volatile("" : "+s"(w1p));

    float xs4 = x4[cur.s];
    float xd4 = x4[cur.d];
    int e0 = tile * 16;

    // stage net_in = [disp(3), norm, ea(3), xs4, xd4, 0...] into rows 0..15, k 0..31
    if (l < 16) {
      bf16x8 w0, w1;
      w0[0] = (__bf16)cur.pe4[0];
      w0[1] = (__bf16)cur.pe4[1];
      w0[2] = (__bf16)cur.pe4[2];
      w0[3] = (__bf16)cur.pe4[3];
      w0[4] = (__bf16)cur.ea4[0];
      w0[5] = (__bf16)cur.ea4[1];
      w0[6] = (__bf16)cur.ea4[2];
      w0[7] = (__bf16)xs4;
      bf16x8 zz;
#pragma unroll
      for (int q = 0; q < 8; q++) zz[q] = (__bf16)0.f;
      w1 = zz;
      w1[0] = (__bf16)xd4;
      *(bf16x8*)(actw + l * HIDDEN + 0) = w0;
      *(bf16x8*)(actw + l * HIDDEN + 8) = w1;
      *(bf16x8*)(actw + l * HIDDEN + 16) = zz;
      *(bf16x8*)(actw + l * HIDDEN + 24) = zz;
    }

    // layer 1 (K=32 padded)
    f32x4 h1[8];
#pragma unroll
    for (int ct = 0; ct < 8; ct++) {
      f32x4 c;
      c[0] = c[1] = c[2] = c[3] = b1c[ct];
      h1[ct] = c;
    }
    mlp_layer_gB<1>(actw, col, krow, l, w1p, h1);
    stage_relu(actw, col, krow, h1);

    // layer 2 (128x128, resident weights)
    f32x4 h2[8];
#pragma unroll
    for (int ct = 0; ct < 8; ct++) {
      f32x4 c;
      c[0] = c[1] = c[2] = c[3] = b2c[ct];
      h2[ct] = c;
    }
    mlp_layer_rB(actw, col, krow, w2r, h2);
    stage_relu(actw, col, krow, h2);

    // layer 3 (128 -> 3, N padded to 16)
    f32x4 o;
    o[0] = o[1] = o[2] = o[3] = b3c;
    o = mlp_out_rB<4>(actw, col, krow, w3r, o);

    // epilogue: ea += o ; atomic scatter to aggr[dst]
    if (col < 3) {
#pragma unroll
      for (int r = 0; r < 4; r++) {
        int ee = e0 + orow + r;
        if (ee < E) {
          float nv = ea[ee * 4 + col] + o[r];
          ea[ee * 4 + col] = nv;
          atomicAdd(aggr + dstp[ee] * 4 + col, nv);
        }
      }
    }
    tile = nt;
    cur = nxt;
  }
}

// ================= node pass =================
__global__ __launch_bounds__(256, 2) void k_node(
    float* __restrict__ x4, const float* __restrict__ Xc, float* __restrict__ aggr,
    const float* __restrict__ deg, const __bf16* __restrict__ W1f,
    const __bf16* __restrict__ W2f, const __bf16* __restrict__ W3f, const float* __restrict__ b1,
    const float* __restrict__ b2, const float* __restrict__ b3, int ntiles, int n) {
  __shared__ __bf16 act[4][16 * HIDDEN];
  int l = threadIdx.x & 63;
  int widx = threadIdx.x >> 6;
  __bf16* actw = act[widx];
  int wgid = blockIdx.x * 4 + widx;
  int nw = gridDim.x * 4;
  int col = l & 15;
  int krow = l >> 4;
  int orow = krow * 4;

  bf16x8 w2r[4][8];
  load_res8(W2f, l, w2r);
  bf16x8 w3r[4];
  load_res1(W3f, l, w3r);

  float b1c[8], b2c[8];
#pragma unroll
  for (int ct = 0; ct < 8; ct++) {
    b1c[ct] = b1[ct * 16 + col];
    b2c[ct] = b2[ct * 16 + col];
  }
  float b3c = (col == 0) ? b3[0] : 0.f;

  for (int tile = wgid; tile < ntiles; tile += nw) {
    const __bf16* w1p = W1f;
    asm volatile("" : "+s"(w1p));

    int i0 = tile * 16 + col;
    bool vi = i0 < n;
    int i = vi ? i0 : (n - 1);
    float x3 = Xc[i * 6 + 4];
    float xv = x4[i];
    f32x4 ag = *(const f32x4*)(aggr + 4 * i);
    float dg = deg[i];
    float inv = dg > 0.f ? 1.0f / dg : 0.f;

    if (l < 16) {
      if (vi) {
        f32x4 z = {0.f, 0.f, 0.f, 0.f};
        *(f32x4*)(aggr + 4 * i) = z;  // clear for next iteration
      }
      bf16x8 w0, zz;
#pragma unroll
      for (int q = 0; q < 8; q++) zz[q] = (__bf16)0.f;
      w0 = zz;
      w0[0] = (__bf16)x3;
      w0[1] = (__bf16)xv;
      w0[2] = (__bf16)(ag[0] * inv);
      w0[3] = (__bf16)(ag[1] * inv);
      w0[4] = (__bf16)(ag[2] * inv);
      *(bf16x8*)(actw + l * HIDDEN + 0) = w0;
      *(bf16x8*)(actw + l * HIDDEN + 8) = zz;
      *(bf16x8*)(actw + l * HIDDEN + 16) = zz;
      *(bf16x8*)(actw + l * HIDDEN + 24) = zz;
    }

    f32x4 h1[8];
#pragma unroll
    for (int ct = 0; ct < 8; ct++) {
      f32x4 c;
      c[0] = c[1] = c[2] = c[3] = b1c[ct];
      h1[ct] = c;
    }
    mlp_layer_gB<1>(actw, col, krow, l, w1p, h1);
    stage_relu(actw, col, krow, h1);

    f32x4 h2[8];
#pragma unroll
    for (int ct = 0; ct < 8; ct++) {
      f32x4 c;
      c[0] = c[1] = c[2] = c[3] = b2c[ct];
      h2[ct] = c;
    }
    mlp_layer_rB(actw, col, krow, w2r, h2);
    stage_relu(actw, col, krow, h2);

    f32x4 o;
    o[0] = o[1] = o[2] = o[3] = b3c;
    o = mlp_out_rB<4>(actw, col, krow, w3r, o);

    if (col == 0) {
#pragma unroll
      for (int r = 0; r < 4; r++) {
        int ii = tile * 16 + orow + r;
        if (ii < n) x4[ii] = x4[ii] + o[r];
      }
    }
  }
}

// ================= decoder =================
__global__ __launch_bounds__(256, 2) void k_dec(
    const float* __restrict__ x4, const float* __restrict__ Xc, const float* __restrict__ y_prev,
    const __bf16* __restrict__ W1f, const __bf16* __restrict__ W2f,
    const __bf16* __restrict__ W3f, const __bf16* __restrict__ W4f, const float* __restrict__ b1,
    const float* __restrict__ b2, const float* __restrict__ b3, const float* __restrict__ b4,
    float* __restrict__ out, int ntiles, int n) {
  __shared__ __bf16 act[4][16 * HIDDEN];
  int l = threadIdx.x & 63;
  int widx = threadIdx.x >> 6;
  __bf16* actw = act[widx];
  int wgid = blockIdx.x * 4 + widx;
  int nw = gridDim.x * 4;
  int col = l & 15;
  int krow = l >> 4;
  int orow = krow * 4;

  bf16x8 w2r[4][8];
  load_res8(W2f, l, w2r);
  bf16x8 w4r[4];
  load_res1(W4f, l, w4r);

  float b1c[8], b2c[8], b3c[8];
#pragma unroll
  for (int ct = 0; ct < 8; ct++) {
    b1c[ct] = b1[ct * 16 + col];
    b2c[ct] = b2[ct * 16 + col];
    b3c[ct] = b3[ct * 16 + col];
  }
  float b4c = (col == 0) ? b4[0] : 0.f;

  for (int tile = wgid; tile < ntiles; tile += nw) {
    const __bf16* w1p = W1f;
    const __bf16* w3p = W3f;
    asm volatile("" : "+s"(w1p), "+s"(w3p));

    int i0 = tile * 16 + col;
    bool vi = i0 < n;
    int i = vi ? i0 : (n - 1);

    if (l < 16) {
      bf16x8 w0, zz;
#pragma unroll
      for (int q = 0; q < 8; q++) zz[q] = (__bf16)0.f;
      w0 = zz;
      w0[0] = (__bf16)Xc[i * 6 + 0];
      w0[1] = (__bf16)Xc[i * 6 + 1];
      w0[2] = (__bf16)Xc[i * 6 + 2];
      w0[3] = (__bf16)Xc[i * 6 + 4];
      w0[4] = (__bf16)x4[i];
      *(bf16x8*)(actw + l * HIDDEN + 0) = w0;
      *(bf16x8*)(actw + l * HIDDEN + 8) = zz;
      *(bf16x8*)(actw + l * HIDDEN + 16) = zz;
      *(bf16x8*)(actw + l * HIDDEN + 24) = zz;
    }

    f32x4 h1[8];
#pragma unroll
    for (int ct = 0; ct < 8; ct++) {
      f32x4 c;
      c[0] = c[1] = c[2] = c[3] = b1c[ct];
      h1[ct] = c;
    }
    mlp_layer_gB<1>(actw, col, krow, l, w1p, h1);
    stage_relu(actw, col, krow, h1);

    f32x4 h2[8];
#pragma unroll
    for (int ct = 0; ct < 8; ct++) {
      f32x4 c;
      c[0] = c[1] = c[2] = c[3] = b2c[ct];
      h2[ct] = c;
    }
    mlp_layer_rB(actw, col, krow, w2r, h2);
    stage_relu(actw, col, krow, h2);

    f32x4 h3[8];
#pragma unroll
    for (int ct = 0; ct < 8; ct++) {
      f32x4 c;
      c[0] = c[1] = c[2] = c[3] = b3c[ct];
      h3[ct] = c;
    }
    mlp_layer_gB<4>(actw, col, krow, l, w3p, h3);
    stage_relu(actw, col, krow, h3);

    f32x4 o;
    o[0] = o[1] = o[2] = o[3] = b4c;
    o = mlp_out_rB<4>(actw, col, krow, w4r, o);

    if (col == 0) {
#pragma unroll
      for (int r = 0; r < 4; r++) {
        int ii = tile * 16 + orow + r;
        if (ii < n) out[ii] = y_prev[ii] + o[r];
      }
    }
  }
}

// ================= host =================
extern "C" void kernel_launch(void* const* d_in, const int* in_sizes, int n_in, void* d_out,
                              int out_size, void* d_ws, size_t ws_size, hipStream_t stream) {
  const float* Xc = (const float*)d_in[0];
  const float* y_prev = (const float*)d_in[1];
  const int* edge = (const int*)d_in[2];
  const float* ew1 = (const float*)d_in[4];
  const float* eb1 = (const float*)d_in[5];
  const float* ew2 = (const float*)d_in[6];
  const float* eb2 = (const float*)d_in[7];
  const float* ew3 = (const float*)d_in[8];
  const float* eb3 = (const float*)d_in[9];
  const float* nw1 = (const float*)d_in[10];
  const float* nb1 = (const float*)d_in[11];
  const float* nw2 = (const float*)d_in[12];
  const float* nb2 = (const float*)d_in[13];
  const float* nw3 = (const float*)d_in[14];
  const float* nb3 = (const float*)d_in[15];
  const float* dw1 = (const float*)d_in[16];
  const float* db1 = (const float*)d_in[17];
  const float* dw2 = (const float*)d_in[18];
  const float* db2 = (const float*)d_in[19];
  const float* dw3 = (const float*)d_in[20];
  const float* db3 = (const float*)d_in[21];
  const float* dw4 = (const float*)d_in[22];
  const float* db4 = (const float*)d_in[23];

  int n = in_sizes[0] / 6;
  int E = in_sizes[2] / 2;
  const int* srcp = edge;
  const int* dstp = edge + E;

  __bf16* wb = (__bf16*)d_ws;
  float* fbase = (float*)((char*)d_ws + (size_t)WB_TOTAL * 2);
  size_t na = ((size_t)n + 3) & ~(size_t)3;
  float* x4 = fbase;
  float* deg = fbase + na;
  float* aggr = fbase + 2 * na;
  float* pe = fbase + 6 * na;
  float* ea = fbase + 6 * na + 4 * (size_t)E;

  size_t need = (size_t)WB_TOTAL * 2 + (6 * na + 8 * (size_t)E) * 4;
  if (ws_size < need) return;  // workspace too small -> fail loudly

  dim3 B(256);
  k_prep<<<dim3((WB_TOTAL + 255) / 256), B, 0, stream>>>(ew1, ew2, ew3, nw1, nw2, nw3, dw1, dw2,
                                                         dw3, dw4, wb);
  k_init_nodes<<<dim3((n + 255) / 256), B, 0, stream>>>(y_prev, x4, deg, aggr, n);
  k_init_edges<<<dim3((E + 255) / 256), B, 0, stream>>>(Xc, y_prev, srcp, dstp, pe, ea, deg, E);

  int etiles = (E + 15) / 16;
  int vtiles = (n + 15) / 16;
  for (int it = 0; it < 3; it++) {
    k_edge<<<dim3(512), B, 0, stream>>>(x4, pe, ea, srcp, dstp, wb + WB_W1E, wb + WB_W2E,
                                        wb + WB_W3E, eb1, eb2, eb3, aggr, etiles, E);
    k_node<<<dim3(512), B, 0, stream>>>(x4, Xc, aggr, deg, wb + WB_W1N, wb + WB_W2N, wb + WB_W3N,
                                        nb1, nb2, nb3, vtiles, n);
  }
  k_dec<<<dim3(512), B, 0, stream>>>(x4, Xc, y_prev, wb + WB_W1D, wb + WB_W2D, wb + WB_W3D,
                                     wb + WB_W4D, db1, db2, db3, db4, (float*)d_out, vtiles, n);
}